// Round 11
// baseline (142.595 us; speedup 1.0000x reference)
//
#include <hip/hip_runtime.h>
#include <cstdint>

#define NN 2048
#define LOG2E 1.4426950408889634f

typedef __attribute__((ext_vector_type(8))) short bf16x8;
typedef __attribute__((ext_vector_type(4))) float f32x4;

__device__ __forceinline__ unsigned short f2bf(float x){
  union { float f; unsigned u; } v; v.f = x;
  unsigned r = v.u + 0x7FFFu + ((v.u >> 16) & 1u);
  return (unsigned short)(r >> 16);
}
__device__ __forceinline__ unsigned pack2(float a, float b){
  return (unsigned)f2bf(a) | ((unsigned)f2bf(b) << 16);
}
// pack two already-truncated uints (value & 0xFFFF0000) in one v_perm
__device__ __forceinline__ unsigned permpack(unsigned hi, unsigned lo){
  return __builtin_amdgcn_perm(hi, lo, 0x07060302u);
}

// ---------------- K0: adj->bitmask (blocks 0..511, 4 rows each, float4+shuffle-pack)
// ----------------     + W^T bf16 (blocks 512..767) ----------------
__global__ __launch_bounds__(256) void k_prep(const float* __restrict__ adj,
                                              const float* __restrict__ W,
                                              unsigned long long* __restrict__ ab,
                                              unsigned short* __restrict__ Wt){
  const int tid = threadIdx.x;
  const int bid = blockIdx.x;
  if (bid < 512){
    const int lane = tid & 63;
    unsigned* ab32 = (unsigned*)ab;
    #pragma unroll
    for (int r = 0; r < 4; r++){
      const int row = bid * 4 + r;
      #pragma unroll
      for (int part = 0; part < 2; part++){
        float4 v = ((const float4*)(adj + (size_t)row * NN))[part * 256 + tid];
        unsigned n = (v.x != 0.f ? 1u : 0u) | (v.y != 0.f ? 2u : 0u)
                   | (v.z != 0.f ? 4u : 0u) | (v.w != 0.f ? 8u : 0u);
        unsigned m;
        m = __shfl_xor(n, 1); n = (lane & 1) ? (m | (n << 4))  : (n | (m << 4));
        m = __shfl_xor(n, 2); n = (lane & 2) ? (m | (n << 8))  : (n | (m << 8));
        m = __shfl_xor(n, 4); n = (lane & 4) ? (m | (n << 16)) : (n | (m << 16));
        if ((lane & 7) == 0)
          ab32[row * 64 + part * 32 + (tid >> 3)] = n;
      }
    }
  } else {
    int g = (bid - 512) * 256 + tid;   // g = o*256 + k
    int o = g >> 8, k = g & 255;
    Wt[g] = f2bf(W[k * 256 + o]);
  }
}

// ---------------- K1: fused Wh=h@W -> s1,s2 (log2e-scaled) + WhT(bf16) ----------------
// grid 256, 512 threads (8 waves). BM=64, BO=256 (wave owns 32 cols), BK=64.
// FRAG-LINEAR As: wave w stages A-fragment f=w; LDS writes/reads lane-linear
// ds_*_b128 => conflict-free. One barrier per stage. (round-0 proven version;
// round-10 BM=32 variant was neutral — reverted)
__global__ __launch_bounds__(512, 2) void k_fused_gemm(const float* __restrict__ h,
                                                       const unsigned short* __restrict__ Wt,
                                                       const float* __restrict__ a,
                                                       unsigned short* __restrict__ WhT,
                                                       float* __restrict__ s1c,
                                                       float* __restrict__ s2c){
  __shared__ __align__(16) unsigned char As[2 * 8192];     // 2 bufs x 8 frags x 1 KB
  __shared__ __align__(16) unsigned short Ts[256 * 72];    // 36864 B
  __shared__ float s1p[8][64], s2p[8][64];                 //  4096 B
  const int tid = threadIdx.x;
  const int r0 = blockIdx.x * 64;
  const int b  = r0 >> 11;
  const int i0 = r0 & (NN - 1);
  const int w = tid >> 6, lane = tid & 63, lhi = lane >> 4, llo = lane & 15;
  const int wc = w * 32;
  const int sit = w >> 1, skk = w & 1;          // staging role: frag (sit,skk)
  const int srow = sit * 16 + llo;              // A row this thread stages
  const int skol = skk * 32 + lhi * 8;          // A col segment

  f32x4 acc[4][2];
  #pragma unroll
  for (int i = 0; i < 4; i++)
    #pragma unroll
    for (int j = 0; j < 2; j++){ acc[i][j][0]=0.f; acc[i][j][1]=0.f; acc[i][j][2]=0.f; acc[i][j][3]=0.f; }

  // prefetch all 4 k-tiles of this thread's A-frag slice
  float4 hv[4][2];
  #pragma unroll
  for (int t = 0; t < 4; t++){
    const float* hp = h + (size_t)(r0 + srow) * 256 + t * 64 + skol;
    hv[t][0] = *(const float4*)hp;
    hv[t][1] = *(const float4*)(hp + 4);
  }

  auto loadB = [&](int k0, bf16x8* dst){
    #pragma unroll
    for (int ot = 0; ot < 2; ot++)
      #pragma unroll
      for (int kk = 0; kk < 2; kk++)
        dst[ot * 2 + kk] = *(const bf16x8*)(Wt + (size_t)(wc + ot * 16 + llo) * 256 + k0 + kk * 32 + lhi * 8);
  };
  bf16x8 bfr[2][4];
  loadB(0, bfr[0]);

  #pragma unroll
  for (int t = 0; t < 4; t++){
    uint4 q = make_uint4(pack2(hv[t][0].x, hv[t][0].y), pack2(hv[t][0].z, hv[t][0].w),
                         pack2(hv[t][1].x, hv[t][1].y), pack2(hv[t][1].z, hv[t][1].w));
    *(uint4*)&As[(t & 1) * 8192 + w * 1024 + lane * 16] = q;   // lane-linear write
    __syncthreads();
    if (t < 3) loadB((t + 1) * 64, bfr[(t + 1) & 1]);
    bf16x8 af[2][4];                              // [kk][it], lane-linear reads
    #pragma unroll
    for (int kk = 0; kk < 2; kk++)
      #pragma unroll
      for (int it = 0; it < 4; it++)
        af[kk][it] = *(const bf16x8*)&As[(t & 1) * 8192 + (it * 2 + kk) * 1024 + lane * 16];
    #pragma unroll
    for (int kk = 0; kk < 2; kk++)
      #pragma unroll
      for (int it = 0; it < 4; it++)
        #pragma unroll
        for (int ot = 0; ot < 2; ot++)
          acc[it][ot] = __builtin_amdgcn_mfma_f32_16x16x32_bf16(af[kk][it], bfr[t & 1][ot * 2 + kk], acc[it][ot], 0, 0, 0);
  }

  // ---- epilogue 1: s1/s2 partial dots (log2e folded) ----
  float a1v[2], a2v[2];
  #pragma unroll
  for (int ot = 0; ot < 2; ot++){
    a1v[ot] = a[wc + ot * 16 + llo] * LOG2E;
    a2v[ot] = a[256 + wc + ot * 16 + llo] * LOG2E;
  }
  #pragma unroll
  for (int it = 0; it < 4; it++){
    #pragma unroll
    for (int q = 0; q < 4; q++){
      float p1 = acc[it][0][q] * a1v[0] + acc[it][1][q] * a1v[1];
      float p2 = acc[it][0][q] * a2v[0] + acc[it][1][q] * a2v[1];
      #pragma unroll
      for (int o = 1; o < 16; o <<= 1){ p1 += __shfl_xor(p1, o); p2 += __shfl_xor(p2, o); }
      if (llo == 0){
        s1p[w][it * 16 + lhi * 4 + q] = p1;
        s2p[w][it * 16 + lhi * 4 + q] = p2;
      }
    }
  }

  // ---- epilogue 2: transpose acc (bf16, round) into Ts[o][i_local] ----
  #pragma unroll
  for (int it = 0; it < 4; it++){
    #pragma unroll
    for (int ot = 0; ot < 2; ot++){
      int o = wc + ot * 16 + llo;
      uint2 u = make_uint2(pack2(acc[it][ot][0], acc[it][ot][1]),
                           pack2(acc[it][ot][2], acc[it][ot][3]));
      *(uint2*)&Ts[o * 72 + it * 16 + lhi * 4] = u;
    }
  }
  __syncthreads();

  if (tid < 64){
    float t1 = 0.f, t2 = 0.f;
    #pragma unroll
    for (int g = 0; g < 8; g++){ t1 += s1p[g][tid]; t2 += s2p[g][tid]; }
    s1c[r0 + tid] = t1;
    s2c[r0 + tid] = t2;
  }
  #pragma unroll
  for (int p = 0; p < 4; p++){
    int o = p * 64 + (tid >> 3), col = (tid & 7) * 8;
    *(uint4*)(WhT + (size_t)(b * 256 + o) * 2048 + i0 + col) = *(const uint4*)&Ts[o * 72 + col];
  }
}

// ---------------- K2: h' = softmax(P) @ Wh ----------------
// grid 256 (b=bid&7 XCD-affine), 512 threads. BM=64, BO=256.
// NEW (round 11): REDUNDANT-COMPUTE, ZERO-BARRIER j-loop. Ten variants showed
// the ~43 us floor is the cooperative structure itself (P exchanged via LDS =>
// barriers => phase lockstep). Here each wave recomputes ALL 8 P-fragments per
// chunk itself — the computing thread's (row=it*16+llo, cols=kk*32+lhi*8)
// layout IS the MFMA A-fragment layout, so P goes straight from VALU to MFMA
// in registers. No Ps buffer, no staging writes, no af reads, NO BARRIERS in
// the 32-chunk loop; waves free-run. Cost: 8x redundant P VALU (~22 us floor,
// < 43 us of lockstep stalls). LDS keeps only read-only broadcast tables
// (E1/E2/bits). Row-sums via MFMA against ones-B (denominator lands in C-lane
// layout; shuffle-reduce + rsp LDS + 2 barriers deleted). Numerics: proven
// p = max(E1*k1, E2*k2) form; rowsum sums the same truncated-bf16 values.
__global__ __launch_bounds__(512, 2) void k_attn(const float* __restrict__ s1c,
                                                 const float* __restrict__ s2c,
                                                 const unsigned short* __restrict__ WhT,
                                                 const unsigned long long* __restrict__ ab,
                                                 float* __restrict__ out){
  __shared__ __align__(16) float E1s[2048];                  //  8192 B
  __shared__ __align__(16) float E2s[2048];                  //  8192 B
  __shared__ __align__(16) unsigned char bitsB[64 * 264];    // 16896 B
  __shared__ float s1s[64], red[8];
  const int tid = threadIdx.x;
  const int bid = blockIdx.x;
  const int b = bid & 7, i0 = (bid >> 3) * 64;
  const int w = tid >> 6, lane = tid & 63, lhi = lane >> 4, llo = lane & 15;
  const int wc = w * 32;                         // this wave's 32 output cols

  // B frags for one 64-j chunk: [ot][kk] -> dst[ot*2+kk]
  auto loadB = [&](int j0, bf16x8* dst){
    #pragma unroll
    for (int ot = 0; ot < 2; ot++)
      #pragma unroll
      for (int kk = 0; kk < 2; kk++)
        dst[ot * 2 + kk] = *(const bf16x8*)(WhT + (size_t)(b * 256 + wc + ot * 16 + llo) * 2048 + j0 + kk * 32 + lhi * 8);
  };
  bf16x8 bA[4], bB[4];
  loadB(0, bA);                                  // earliest possible global prefetch

  // ---- preamble: E1=exp2(s2), E2=exp2(.2*s2) (+max), s1 tile, adj mask rows ----
  float4 v = ((const float4*)(s2c + (size_t)b * NN))[tid];
  ((float4*)E1s)[tid] = make_float4(__builtin_amdgcn_exp2f(v.x), __builtin_amdgcn_exp2f(v.y),
                                    __builtin_amdgcn_exp2f(v.z), __builtin_amdgcn_exp2f(v.w));
  ((float4*)E2s)[tid] = make_float4(__builtin_amdgcn_exp2f(0.2f * v.x), __builtin_amdgcn_exp2f(0.2f * v.y),
                                    __builtin_amdgcn_exp2f(0.2f * v.z), __builtin_amdgcn_exp2f(0.2f * v.w));
  float vmax = fmaxf(fmaxf(v.x, v.y), fmaxf(v.z, v.w));
  #pragma unroll
  for (int o = 32; o; o >>= 1) vmax = fmaxf(vmax, __shfl_xor(vmax, o));
  if (lane == 0) red[w] = vmax;
  if (tid < 64) s1s[tid] = s1c[(size_t)b * NN + i0 + tid];
  #pragma unroll
  for (int k = 0; k < 4; k++){
    int g = k * 512 + tid;                       // 0..2047 mask words (u64: row*264 + jc*8)
    unsigned long long mw = ab[(size_t)i0 * 32 + g];
    *(unsigned long long*)&bitsB[(g >> 5) * 264 + (g & 31) * 8] = mw;
  }
  __syncthreads();                               // the ONLY block-wide barrier
  float m2 = red[0];
  #pragma unroll
  for (int g = 1; g < 8; g++) m2 = fmaxf(m2, red[g]);

  // per-thread row constants for its 4 A-fragment rows (it*16 + llo)
  float k1v[4], k2v[4];
  #pragma unroll
  for (int it = 0; it < 4; it++){
    float s1v = s1s[it * 16 + llo];
    float xm = s1v + m2;
    float mv = fmaxf(xm, 0.2f * xm);             // upper bound on row max (lrelu monotone)
    k1v[it] = __builtin_amdgcn_exp2f(s1v - mv);  // p = max(E1*k1, E2*k2)
    k2v[it] = __builtin_amdgcn_exp2f(0.2f * s1v - mv);
  }

  f32x4 acc[4][2], accr[4];
  #pragma unroll
  for (int i = 0; i < 4; i++){
    accr[i][0]=0.f; accr[i][1]=0.f; accr[i][2]=0.f; accr[i][3]=0.f;
    #pragma unroll
    for (int j = 0; j < 2; j++){ acc[i][j][0]=0.f; acc[i][j][1]=0.f; acc[i][j][2]=0.f; acc[i][j][3]=0.f; }
  }
  bf16x8 onesB;                                  // bf16 1.0 x8 for rowsum MFMA
  { union { unsigned u[4]; bf16x8 v2; } t;
    t.u[0]=0x3F803F80u; t.u[1]=0x3F803F80u; t.u[2]=0x3F803F80u; t.u[3]=0x3F803F80u;
    onesB = t.v2; }

  // one 64-j chunk: build all 8 A-frags in-register, 24 MFMA, no sync
  auto chunkBody = [&](int jc, bf16x8* curB, bf16x8* nxtB, bool pf){
    unsigned long long bw[4];                    // mask u64 per row-group
    #pragma unroll
    for (int it = 0; it < 4; it++)
      bw[it] = *(const unsigned long long*)&bitsB[(it * 16 + llo) * 264 + jc * 8];
    if (pf) loadB((jc + 1) * 64, nxtB);
    #pragma unroll
    for (int kk = 0; kk < 2; kk++){
      const int j0 = jc * 64 + kk * 32 + lhi * 8;
      float4 xa = *(const float4*)&E1s[j0];
      float4 xb = *(const float4*)&E1s[j0 + 4];
      float4 ya = *(const float4*)&E2s[j0];
      float4 yb = *(const float4*)&E2s[j0 + 4];
      float e1[8] = {xa.x, xa.y, xa.z, xa.w, xb.x, xb.y, xb.z, xb.w};
      float e2[8] = {ya.x, ya.y, ya.z, ya.w, yb.x, yb.y, yb.z, yb.w};
      #pragma unroll
      for (int it = 0; it < 4; it++){
        unsigned b8 = (unsigned)(bw[it] >> ((kk * 4 + lhi) * 8)) & 0xFFu;
        unsigned pu[8];
        #pragma unroll
        for (int e = 0; e < 8; e++){
          float p = fmaxf(e1[e] * k1v[it], e2[e] * k2v[it]);
          unsigned m = ((b8 >> e) & 1u) ? 0xFFFF0000u : 0u;
          pu[e] = __float_as_uint(p) & m;
        }
        union { unsigned u[4]; bf16x8 v2; } afu;
        afu.u[0] = permpack(pu[1], pu[0]); afu.u[1] = permpack(pu[3], pu[2]);
        afu.u[2] = permpack(pu[5], pu[4]); afu.u[3] = permpack(pu[7], pu[6]);
        acc[it][0] = __builtin_amdgcn_mfma_f32_16x16x32_bf16(afu.v2, curB[kk],     acc[it][0], 0, 0, 0);
        acc[it][1] = __builtin_amdgcn_mfma_f32_16x16x32_bf16(afu.v2, curB[2 + kk], acc[it][1], 0, 0, 0);
        accr[it]   = __builtin_amdgcn_mfma_f32_16x16x32_bf16(afu.v2, onesB,        accr[it],   0, 0, 0);
      }
    }
  };

  for (int jc2 = 0; jc2 < 32; jc2 += 2){         // static dbuf, 2-chunk unroll
    chunkBody(jc2,     bA, bB, true);
    chunkBody(jc2 + 1, bB, bA, jc2 + 1 < 31);
  }

  // ---- epilogue: denominator is accr[it][q] (already in C-lane layout) ----
  #pragma unroll
  for (int it = 0; it < 4; it++){
    f32x4 linv;
    #pragma unroll
    for (int q = 0; q < 4; q++) linv[q] = 1.0f / accr[it][q];
    #pragma unroll
    for (int ot = 0; ot < 2; ot++){
      int col = wc + ot * 16 + llo;
      #pragma unroll
      for (int q = 0; q < 4; q++){
        int row = it * 16 + lhi * 4 + q;
        out[(size_t)(b * NN + i0 + row) * 256 + col] = acc[it][ot][q] * linv[q];
      }
    }
  }
}

extern "C" void kernel_launch(void* const* d_in, const int* in_sizes, int n_in,
                              void* d_out, int out_size, void* d_ws, size_t ws_size,
                              hipStream_t stream) {
  const float* h   = (const float*)d_in[0];
  const float* adj = (const float*)d_in[1];
  const float* W   = (const float*)d_in[2];
  const float* a   = (const float*)d_in[3];
  float* out = (float*)d_out;

  char* ws = (char*)d_ws;
  unsigned short* WhT      = (unsigned short*)(ws);                 // 8,388,608 B
  unsigned short* Wt       = (unsigned short*)(ws + 8388608);       //   131,072 B
  unsigned long long* ab   = (unsigned long long*)(ws + 8519680);   //   524,288 B
  float* s1c               = (float*)(ws + 9043968);                //    65,536 B
  float* s2c               = (float*)(ws + 9109504);                //    65,536 B

  hipLaunchKernelGGL(k_prep,       dim3(768), dim3(256), 0, stream, adj, W, ab, Wt);
  hipLaunchKernelGGL(k_fused_gemm, dim3(256), dim3(512), 0, stream, h, Wt, a, WhT, s1c, s2c);
  hipLaunchKernelGGL(k_attn,       dim3(256), dim3(512), 0, stream, s1c, s2c, WhT, ab, out);
}